// Round 13
// baseline (522.150 us; speedup 1.0000x reference)
//
#include <hip/hip_runtime.h>
#include <hip/hip_fp16.h>
#include <cstdint>
#include <cstddef>

#define NN 100000      // nodes
#define NE 1600000     // edges
#define HID 100
#define INF 16
#define NP 100096      // per-group histogram pitch (64B-aligned copies)

typedef _Float16 f16x8 __attribute__((ext_vector_type(8)));
typedef float f32x4 __attribute__((ext_vector_type(4)));

// ---- fp16 helpers (h, r stored fp16; all accumulation fp32) ----
__device__ __forceinline__ float2 up_f16(unsigned int u) {
  __half2 h = *reinterpret_cast<const __half2*>(&u);
  return __half22float2(h);
}
__device__ __forceinline__ unsigned int pk_f16(float lo, float hi) {
  __half2 h = __floats2half2_rn(lo, hi);
  return *reinterpret_cast<const unsigned int*>(&h);
}
__device__ __forceinline__ f16x8 as_f16x8(uint4 v) {
  union { uint4 u; f16x8 f; } c; c.u = v; return c.f;
}

// ---------------- CSR build ----------------
// 8-way privatized histogram: group g = blockIdx&7 ~ XCD (round-robin
// dispatch) -> atomics stay in one XCD's L2; no cross-XCD line ping-pong
// (R11: single-table k_hist had WRITE_SIZE 56MB for 6.4MB payload).
// rank = within-(group,dst) rank from atomicAdd return.
__global__ void k_hist(const int* __restrict__ dst, int* __restrict__ deg8,
                       int* __restrict__ rank) {
  int e = blockIdx.x * 256 + threadIdx.x;
  if (e >= NE) return;
  int g = blockIdx.x & 7;
  rank[e] = atomicAdd(&deg8[g * NP + dst[e]], 1);
}

// per-node: total degree + per-group exclusive prefix (gpre)
__global__ void k_sumdeg(const int* __restrict__ deg8, int* __restrict__ gpre,
                         int* __restrict__ deg) {
  int n = blockIdx.x * 256 + threadIdx.x;
  if (n >= NN) return;
  int run = 0;
  #pragma unroll
  for (int g = 0; g < 8; ++g) {
    int t = deg8[g * NP + n];
    gpre[g * NP + n] = run;
    run += t;
  }
  deg[n] = run;
}

__global__ void k_scan1(const int* __restrict__ deg, int* __restrict__ offs,
                        int* __restrict__ bsum) {
  __shared__ int s[256];
  int t = threadIdx.x;
  int i = blockIdx.x * 256 + t;
  int v = (i < NN) ? deg[i] : 0;
  s[t] = v; __syncthreads();
  for (int off = 1; off < 256; off <<= 1) {
    int x = (t >= off) ? s[t - off] : 0;
    __syncthreads();
    s[t] += x;
    __syncthreads();
  }
  if (i < NN) offs[i] = s[t] - v;
  if (t == 255) bsum[blockIdx.x] = s[255];
}

__global__ void k_scan2(int* __restrict__ bsum, int nb) {
  __shared__ int s[512];
  int t = threadIdx.x;
  int v = (t < nb) ? bsum[t] : 0;
  s[t] = v; __syncthreads();
  for (int off = 1; off < 512; off <<= 1) {
    int x = (t >= off) ? s[t - off] : 0;
    __syncthreads();
    s[t] += x;
    __syncthreads();
  }
  if (t < nb) bsum[t] = s[t] - v;
}

__global__ void k_scan3(int* __restrict__ offs, const int* __restrict__ bsum) {
  int i = blockIdx.x * 256 + threadIdx.x;
  if (i < NN) offs[i] += bsum[i >> 8];
  else if (i == NN) offs[NN] = NE;
}

// atomic-free scatter: p = offs[d] + gpre[g][d] + rank. Same grid shape as
// k_hist -> blockIdx&7 reproduces each edge's group.
__global__ void k_fill(const int* __restrict__ src, const int* __restrict__ dst,
                       const float* __restrict__ ef, const int* __restrict__ offs,
                       const int* __restrict__ gpre, const int* __restrict__ rank,
                       unsigned long long* __restrict__ epack) {
  int e = blockIdx.x * 256 + threadIdx.x;
  if (e >= NE) return;
  int g = blockIdx.x & 7;
  int d = dst[e];
  int p = offs[d] + gpre[g * NP + d] + rank[e];
  unsigned long long v = (unsigned int)src[e] |
                         ((unsigned long long)(unsigned int)__float_as_int(ef[e]) << 32);
  epack[p] = v;
}

// ---- W pre-pack into per-lane MFMA B-fragments (fp16), once per layer ----
__device__ __forceinline__ float wval(const float* W, int kp, int col) {
  if (col >= HID) return 0.f;
  if (kp < 128) return (kp < 100) ? W[kp * HID + col] : 0.f;
  int k2 = kp - 128;
  return (k2 < 100) ? W[(100 + k2) * HID + col] : 0.f;
}
__global__ void k_wpack(const float* __restrict__ W, uint4* __restrict__ Bp) {
  int tid = blockIdx.x * 256 + threadIdx.x;
  if (tid >= 56 * 64) return;
  int lane = tid & 63, f = tid >> 6;
  int s = f / 7, n = f % 7;
  int col = n * 16 + (lane & 15);
  int kb = s * 32 + (lane >> 4) * 8;
  unsigned int u0 = pk_f16(wval(W, kb + 0, col), wval(W, kb + 1, col));
  unsigned int u1 = pk_f16(wval(W, kb + 2, col), wval(W, kb + 3, col));
  unsigned int u2 = pk_f16(wval(W, kb + 4, col), wval(W, kb + 5, col));
  unsigned int u3 = pk_f16(wval(W, kb + 6, col), wval(W, kb + 7, col));
  Bp[tid] = make_uint4(u0, u1, u2, u3);
}

// ---------------- lift: h16 = fp16(tanh(x @ Wl + bl)) ----------------
// Compute thread-per-node, then COALESCED store via LDS staging (R11:
// direct 8B stores at 200B lane-stride caused 68MB WRITE for 20MB payload).
__global__ __launch_bounds__(256) void k_lift(const float* __restrict__ x,
                                              const float* __restrict__ Wl,
                                              const float* __restrict__ bl,
                                              unsigned short* __restrict__ h16) {
  __shared__ uint2 sh[256][25];     // 51,200 B
  int t = threadIdx.x;
  int n = blockIdx.x * 256 + t;
  int nc = n < NN ? n : NN - 1;     // clamp OOB threads (stores bounded below)
  const float4* W4 = (const float4*)Wl;        // [16][25] float4
  const float4* b4 = (const float4*)bl;
  float4 acc[25];
  #pragma unroll
  for (int j = 0; j < 25; ++j) acc[j] = b4[j];
  const float4* xr = (const float4*)(x + (size_t)nc * INF);
  for (int k4 = 0; k4 < 4; ++k4) {
    float4 xv = xr[k4];
    #pragma unroll
    for (int c = 0; c < 4; ++c) {
      float xs = (&xv.x)[c];
      int k = k4 * 4 + c;
      #pragma unroll
      for (int j = 0; j < 25; ++j) {
        acc[j].x = fmaf(xs, W4[k * 25 + j].x, acc[j].x);
        acc[j].y = fmaf(xs, W4[k * 25 + j].y, acc[j].y);
        acc[j].z = fmaf(xs, W4[k * 25 + j].z, acc[j].z);
        acc[j].w = fmaf(xs, W4[k * 25 + j].w, acc[j].w);
      }
    }
  }
  #pragma unroll
  for (int j = 0; j < 25; ++j) {
    float4 v = acc[j];
    sh[t][j] = make_uint2(pk_f16(tanhf(v.x), tanhf(v.y)),
                          pk_f16(tanhf(v.z), tanhf(v.w)));
  }
  __syncthreads();
  // dense coalesced flush: 3200 uint4 per block; global bound NN*100/8
  const uint4* shv = (const uint4*)sh;
  uint4* ov = (uint4*)h16;
  size_t gbase = (size_t)blockIdx.x * 3200;
  #pragma unroll
  for (int i = 0; i < 13; ++i) {
    int idx = i * 256 + t;
    if (idx < 3200 && gbase + idx < 1250000) ov[gbase + idx] = shv[idx];
  }
}

// -------- reduce: red16[n][f] = fp16(sum over in-edges of h16[src][f]*w) --------
__global__ __launch_bounds__(256) void k_reduce(const unsigned short* __restrict__ h16,
                                                const int* __restrict__ offs,
                                                const int2* __restrict__ ep,
                                                unsigned int* __restrict__ red16) {
  int wid = (blockIdx.x * 256 + threadIdx.x) >> 6;
  int node = __builtin_amdgcn_readfirstlane(wid);
  int lane = threadIdx.x & 63;
  int lc = lane < 25 ? lane : 24;
  int beg = offs[node], end = offs[node + 1];
  const uint2* __restrict__ h2 = (const uint2*)h16;   // row = 25 uint2
  float4 acc = make_float4(0.f, 0.f, 0.f, 0.f);
  int i = beg;
  for (; i + 4 <= end; i += 4) {
    int2 e0 = ep[i + 0], e1 = ep[i + 1], e2 = ep[i + 2], e3 = ep[i + 3];
    uint2 v0 = h2[(size_t)e0.x * 25 + lc];
    uint2 v1 = h2[(size_t)e1.x * 25 + lc];
    uint2 v2 = h2[(size_t)e2.x * 25 + lc];
    uint2 v3 = h2[(size_t)e3.x * 25 + lc];
    float w0 = __int_as_float(e0.y), w1 = __int_as_float(e1.y);
    float w2 = __int_as_float(e2.y), w3 = __int_as_float(e3.y);
    float2 a0 = up_f16(v0.x), b0 = up_f16(v0.y);
    float2 a1 = up_f16(v1.x), b1 = up_f16(v1.y);
    float2 a2 = up_f16(v2.x), b2 = up_f16(v2.y);
    float2 a3 = up_f16(v3.x), b3 = up_f16(v3.y);
    acc.x = fmaf(w0, a0.x, acc.x); acc.y = fmaf(w0, a0.y, acc.y);
    acc.z = fmaf(w0, b0.x, acc.z); acc.w = fmaf(w0, b0.y, acc.w);
    acc.x = fmaf(w1, a1.x, acc.x); acc.y = fmaf(w1, a1.y, acc.y);
    acc.z = fmaf(w1, b1.x, acc.z); acc.w = fmaf(w1, b1.y, acc.w);
    acc.x = fmaf(w2, a2.x, acc.x); acc.y = fmaf(w2, a2.y, acc.y);
    acc.z = fmaf(w2, b2.x, acc.z); acc.w = fmaf(w2, b2.y, acc.w);
    acc.x = fmaf(w3, a3.x, acc.x); acc.y = fmaf(w3, a3.y, acc.y);
    acc.z = fmaf(w3, b3.x, acc.z); acc.w = fmaf(w3, b3.y, acc.w);
  }
  for (; i < end; ++i) {
    int2 e0 = ep[i];
    uint2 v0 = h2[(size_t)e0.x * 25 + lc];
    float w0 = __int_as_float(e0.y);
    float2 a0 = up_f16(v0.x), b0 = up_f16(v0.y);
    acc.x = fmaf(w0, a0.x, acc.x); acc.y = fmaf(w0, a0.y, acc.y);
    acc.z = fmaf(w0, b0.x, acc.z); acc.w = fmaf(w0, b0.y, acc.w);
  }
  if (lane < 25) {
    ((uint2*)red16)[(size_t)node * 25 + lane] =
        make_uint2(pk_f16(acc.x, acc.y), pk_f16(acc.z, acc.w));
  }
}

// -------- mlp (MFMA): out16 = fp16(relu([h|r] @ W + b)) --------
// C/D mapping (m89-verified): col = lane&15, row = (lane>>4)*4 + reg.
__global__ __launch_bounds__(256) void k_mlp(const unsigned int* __restrict__ hp,
                                             const unsigned int* __restrict__ rp,
                                             const uint4* __restrict__ Bpk,
                                             const float* __restrict__ bias,
                                             unsigned short* __restrict__ out16) {
  __shared__ unsigned int xs[64 * 132];
  const int t = threadIdx.x;
  const int w = t >> 6, lane = t & 63;
  const int blk = blockIdx.x;
  const size_t base2 = (size_t)blk * 3200;
  const size_t limit2 = (size_t)NN * 50;

  for (int i = t; i < 64 * 28; i += 256) {
    int row = i / 28, c = i % 28;
    int col = (c < 14) ? (50 + c) : (100 + c);
    xs[row * 132 + col] = 0;
  }
  for (int i = t; i < 3200; i += 256) {
    int row = i / 50, c = i % 50;
    size_t g = base2 + i; if (g >= limit2) g = limit2 - 1;
    xs[row * 132 + c] = hp[g];
    xs[row * 132 + 64 + c] = rp[g];
  }
  __syncthreads();

  const int rowA = (w << 4) + (lane & 15);
  const int kg = lane >> 4;
  f32x4 acc[7];
  #pragma unroll
  for (int n = 0; n < 7; ++n) {
    int c = n * 16 + (lane & 15);
    float bv = (c < HID) ? bias[c] : 0.f;
    acc[n] = (f32x4){bv, bv, bv, bv};
  }
  const uint4* bp = Bpk + lane;
  #pragma unroll
  for (int s = 0; s < 8; ++s) {
    uint4 av = *reinterpret_cast<const uint4*>(&xs[rowA * 132 + s * 16 + kg * 4]);
    f16x8 af = as_f16x8(av);
    #pragma unroll
    for (int n = 0; n < 7; ++n) {
      f16x8 bf = as_f16x8(bp[(s * 7 + n) * 64]);
      acc[n] = __builtin_amdgcn_mfma_f32_16x16x32_f16(af, bf, acc[n], 0, 0, 0);
    }
  }
  const int orow0 = blk * 64 + (w << 4) + (kg << 2);
  const int ocol = lane & 15;
  #pragma unroll
  for (int n = 0; n < 7; ++n) {
    int c = n * 16 + ocol;
    if (c < HID) {
      #pragma unroll
      for (int q = 0; q < 4; ++q) {
        int rr = orow0 + q;
        if (rr < NN) {
          float v = fmaxf(acc[n][q], 0.f);
          out16[(size_t)rr * HID + c] = __half_as_ushort(__float2half(v));
        }
      }
    }
  }
}

// -------- out: sigmoid(h16 @ Wo + bo), thread per node --------
__global__ __launch_bounds__(256) void k_out(const unsigned short* __restrict__ h16,
                                             const float* __restrict__ Wo,
                                             const float* __restrict__ bo,
                                             float* __restrict__ out) {
  int n = blockIdx.x * 256 + threadIdx.x;
  if (n >= NN) return;
  float a0 = bo[0], a1 = bo[1], a2 = bo[2];
  const uint2* hr = (const uint2*)(h16 + (size_t)n * HID);
  for (int k2 = 0; k2 < 25; ++k2) {
    uint2 v = hr[k2];
    float2 fa = up_f16(v.x), fb = up_f16(v.y);
    int k = k2 * 4;
    a0 = fmaf(fa.x, Wo[(k + 0) * 3 + 0], a0); a1 = fmaf(fa.x, Wo[(k + 0) * 3 + 1], a1); a2 = fmaf(fa.x, Wo[(k + 0) * 3 + 2], a2);
    a0 = fmaf(fa.y, Wo[(k + 1) * 3 + 0], a0); a1 = fmaf(fa.y, Wo[(k + 1) * 3 + 1], a1); a2 = fmaf(fa.y, Wo[(k + 1) * 3 + 2], a2);
    a0 = fmaf(fb.x, Wo[(k + 2) * 3 + 0], a0); a1 = fmaf(fb.x, Wo[(k + 2) * 3 + 1], a1); a2 = fmaf(fb.x, Wo[(k + 2) * 3 + 2], a2);
    a0 = fmaf(fb.y, Wo[(k + 3) * 3 + 0], a0); a1 = fmaf(fb.y, Wo[(k + 3) * 3 + 1], a1); a2 = fmaf(fb.y, Wo[(k + 3) * 3 + 2], a2);
  }
  out[(size_t)n * 3 + 0] = 1.f / (1.f + expf(-a0));
  out[(size_t)n * 3 + 1] = 1.f / (1.f + expf(-a1));
  out[(size_t)n * 3 + 2] = 1.f / (1.f + expf(-a2));
}

extern "C" void kernel_launch(void* const* d_in, const int* in_sizes, int n_in,
                              void* d_out, int out_size, void* d_ws, size_t ws_size,
                              hipStream_t stream) {
  const float* x  = (const float*)d_in[0];
  const float* ef = (const float*)d_in[1];
  const int*   src = (const int*)d_in[2];
  const int*   dst = (const int*)d_in[3];
  const float* Wl = (const float*)d_in[4];
  const float* bl = (const float*)d_in[5];
  const float* W1 = (const float*)d_in[6];
  const float* b1 = (const float*)d_in[7];
  const float* W2 = (const float*)d_in[8];
  const float* b2 = (const float*)d_in[9];
  const float* W3 = (const float*)d_in[10];
  const float* b3 = (const float*)d_in[11];
  const float* Wo = (const float*)d_in[12];
  const float* bo = (const float*)d_in[13];
  float* out = (float*)d_out;

  // workspace layout (~93.6 MB, unchanged footprint)
  char* ws = (char*)d_ws;
  unsigned int*   red16  = (unsigned int*)(ws);                 // 20,000,000 B (fp16 reduce out)
  uint4*          Wpk    = (uint4*)(ws + 20000000);             // 3 x 57,344 B
  unsigned short* hA16   = (unsigned short*)(ws + 40000000);    // 20,000,000 B
  unsigned short* hB16   = (unsigned short*)(ws + 60000000);    // 20,000,000 B
  int*            offs   = (int*)(ws + 80000000);               // (NN+1)*4
  int*            deg    = (int*)(ws + 80400128);               // NN*4
  unsigned long long* epack = (unsigned long long*)(ws + 80800256); // NE*8
  int*            bsum   = (int*)(ws + 93600256);               // 391*4
  // CSR-build scratch aliases red16 (all consumed before first k_reduce):
  int*            rank   = (int*)ws;                            // 6,400,000 B
  int*            deg8   = (int*)(ws + 6400000);                // 8*NP*4 = 3,203,072 B
  int*            gpre   = (int*)(ws + 9603072);                // 3,203,072 B

  const int scanBlocks = (NN + 255) / 256;          // 391
  const int mlpBlocks  = (NN + 63) / 64;            // 1563
  uint4* Wpk1 = Wpk;                                // 3584 uint4 each
  uint4* Wpk2 = Wpk + 3584;
  uint4* Wpk3 = Wpk + 7168;

  // ---- CSR build (privatized hist + rank trick, atomic-free fill) ----
  hipMemsetAsync(deg8, 0, 8 * NP * sizeof(int), stream);
  k_hist  <<<(NE + 255) / 256, 256, 0, stream>>>(dst, deg8, rank);
  k_sumdeg<<<scanBlocks, 256, 0, stream>>>(deg8, gpre, deg);
  k_scan1 <<<scanBlocks, 256, 0, stream>>>(deg, offs, bsum);
  k_scan2 <<<1, 512, 0, stream>>>(bsum, scanBlocks);
  k_scan3 <<<scanBlocks, 256, 0, stream>>>(offs, bsum);
  k_fill  <<<(NE + 255) / 256, 256, 0, stream>>>(src, dst, ef, offs, gpre, rank, epack);

  // ---- W fragment pre-pack (fp16) ----
  k_wpack<<<14, 256, 0, stream>>>(W1, Wpk1);
  k_wpack<<<14, 256, 0, stream>>>(W2, Wpk2);
  k_wpack<<<14, 256, 0, stream>>>(W3, Wpk3);

  // ---- network ----
  k_lift<<<scanBlocks, 256, 0, stream>>>(x, Wl, bl, hA16);

  k_reduce<<<NN / 4, 256, 0, stream>>>(hA16, offs, (const int2*)epack, red16);
  k_mlp   <<<mlpBlocks, 256, 0, stream>>>((const unsigned int*)hA16, red16, Wpk1, b1, hB16);

  k_reduce<<<NN / 4, 256, 0, stream>>>(hB16, offs, (const int2*)epack, red16);
  k_mlp   <<<mlpBlocks, 256, 0, stream>>>((const unsigned int*)hB16, red16, Wpk2, b2, hA16);

  k_reduce<<<NN / 4, 256, 0, stream>>>(hA16, offs, (const int2*)epack, red16);
  k_mlp   <<<mlpBlocks, 256, 0, stream>>>((const unsigned int*)hA16, red16, Wpk3, b3, hB16);

  k_out<<<scanBlocks, 256, 0, stream>>>(hB16, Wo, bo, out);
}

// Round 14
// 511.564 us; speedup vs baseline: 1.0207x; 1.0207x over previous
//
#include <hip/hip_runtime.h>
#include <hip/hip_fp16.h>
#include <cstdint>
#include <cstddef>

#define NN 100000      // nodes
#define NE 1600000     // edges
#define HID 100
#define INF 16

typedef _Float16 f16x8 __attribute__((ext_vector_type(8)));
typedef float f32x4 __attribute__((ext_vector_type(4)));

// ---- fp16 helpers (h, r stored fp16; all accumulation fp32) ----
__device__ __forceinline__ float2 up_f16(unsigned int u) {
  __half2 h = *reinterpret_cast<const __half2*>(&u);
  return __half22float2(h);
}
__device__ __forceinline__ unsigned int pk_f16(float lo, float hi) {
  __half2 h = __floats2half2_rn(lo, hi);
  return *reinterpret_cast<const unsigned int*>(&h);
}
__device__ __forceinline__ f16x8 as_f16x8(uint4 v) {
  union { uint4 u; f16x8 f; } c; c.u = v; return c.f;
}

// ---------------- CSR build (R9 scheme) ----------------
// hist + rank: atomicAdd's return value IS edge e's rank within its dst
// segment -> k_fill needs ZERO atomics. NOTE (R13): 8-way XCD privatization
// of this table was a NULL result (identical 67us / 56MB WRITE) -> atomics
// resolve at a shared memory-side point; table layout can't help. ~67us is
// the 1.6M-random-atomic floor.
__global__ void k_hist(const int* __restrict__ dst, int* __restrict__ deg,
                       int* __restrict__ rank) {
  int e = blockIdx.x * 256 + threadIdx.x;
  if (e < NE) rank[e] = atomicAdd(&deg[dst[e]], 1);
}

__global__ void k_scan1(const int* __restrict__ deg, int* __restrict__ offs,
                        int* __restrict__ bsum) {
  __shared__ int s[256];
  int t = threadIdx.x;
  int i = blockIdx.x * 256 + t;
  int v = (i < NN) ? deg[i] : 0;
  s[t] = v; __syncthreads();
  for (int off = 1; off < 256; off <<= 1) {
    int x = (t >= off) ? s[t - off] : 0;
    __syncthreads();
    s[t] += x;
    __syncthreads();
  }
  if (i < NN) offs[i] = s[t] - v;
  if (t == 255) bsum[blockIdx.x] = s[255];
}

__global__ void k_scan2(int* __restrict__ bsum, int nb) {
  __shared__ int s[512];
  int t = threadIdx.x;
  int v = (t < nb) ? bsum[t] : 0;
  s[t] = v; __syncthreads();
  for (int off = 1; off < 512; off <<= 1) {
    int x = (t >= off) ? s[t - off] : 0;
    __syncthreads();
    s[t] += x;
    __syncthreads();
  }
  if (t < nb) bsum[t] = s[t] - v;
}

__global__ void k_scan3(int* __restrict__ offs, const int* __restrict__ bsum) {
  int i = blockIdx.x * 256 + threadIdx.x;
  if (i < NN) offs[i] += bsum[i >> 8];
  else if (i == NN) offs[NN] = NE;
}

// atomic-free scatter: p = offs[dst] + rank.
__global__ void k_fill(const int* __restrict__ src, const int* __restrict__ dst,
                       const float* __restrict__ ef, const int* __restrict__ offs,
                       const int* __restrict__ rank,
                       unsigned long long* __restrict__ epack) {
  int e = blockIdx.x * 256 + threadIdx.x;
  if (e >= NE) return;
  int p = offs[dst[e]] + rank[e];
  unsigned long long v = (unsigned int)src[e] |
                         ((unsigned long long)(unsigned int)__float_as_int(ef[e]) << 32);
  epack[p] = v;
}

// ---- W pre-pack into per-lane MFMA B-fragments (fp16), once per layer ----
__device__ __forceinline__ float wval(const float* W, int kp, int col) {
  if (col >= HID) return 0.f;
  if (kp < 128) return (kp < 100) ? W[kp * HID + col] : 0.f;
  int k2 = kp - 128;
  return (k2 < 100) ? W[(100 + k2) * HID + col] : 0.f;
}
__global__ void k_wpack(const float* __restrict__ W, uint4* __restrict__ Bp) {
  int tid = blockIdx.x * 256 + threadIdx.x;
  if (tid >= 56 * 64) return;
  int lane = tid & 63, f = tid >> 6;
  int s = f / 7, n = f % 7;
  int col = n * 16 + (lane & 15);
  int kb = s * 32 + (lane >> 4) * 8;
  unsigned int u0 = pk_f16(wval(W, kb + 0, col), wval(W, kb + 1, col));
  unsigned int u1 = pk_f16(wval(W, kb + 2, col), wval(W, kb + 3, col));
  unsigned int u2 = pk_f16(wval(W, kb + 4, col), wval(W, kb + 5, col));
  unsigned int u3 = pk_f16(wval(W, kb + 6, col), wval(W, kb + 7, col));
  Bp[tid] = make_uint4(u0, u1, u2, u3);
}

// ---------------- lift: h16 = fp16(tanh(x @ Wl + bl)) ----------------
// Compute thread-per-node, COALESCED store via LDS staging (R13-verified:
// left the top-5; direct 8B stores at 200B stride had 3.4x write-amp).
__global__ __launch_bounds__(256) void k_lift(const float* __restrict__ x,
                                              const float* __restrict__ Wl,
                                              const float* __restrict__ bl,
                                              unsigned short* __restrict__ h16) {
  __shared__ uint2 sh[256][25];     // 51,200 B
  int t = threadIdx.x;
  int n = blockIdx.x * 256 + t;
  int nc = n < NN ? n : NN - 1;
  const float4* W4 = (const float4*)Wl;        // [16][25] float4
  const float4* b4 = (const float4*)bl;
  float4 acc[25];
  #pragma unroll
  for (int j = 0; j < 25; ++j) acc[j] = b4[j];
  const float4* xr = (const float4*)(x + (size_t)nc * INF);
  for (int k4 = 0; k4 < 4; ++k4) {
    float4 xv = xr[k4];
    #pragma unroll
    for (int c = 0; c < 4; ++c) {
      float xs = (&xv.x)[c];
      int k = k4 * 4 + c;
      #pragma unroll
      for (int j = 0; j < 25; ++j) {
        acc[j].x = fmaf(xs, W4[k * 25 + j].x, acc[j].x);
        acc[j].y = fmaf(xs, W4[k * 25 + j].y, acc[j].y);
        acc[j].z = fmaf(xs, W4[k * 25 + j].z, acc[j].z);
        acc[j].w = fmaf(xs, W4[k * 25 + j].w, acc[j].w);
      }
    }
  }
  #pragma unroll
  for (int j = 0; j < 25; ++j) {
    float4 v = acc[j];
    sh[t][j] = make_uint2(pk_f16(tanhf(v.x), tanhf(v.y)),
                          pk_f16(tanhf(v.z), tanhf(v.w)));
  }
  __syncthreads();
  const uint4* shv = (const uint4*)sh;
  uint4* ov = (uint4*)h16;
  size_t gbase = (size_t)blockIdx.x * 3200;
  #pragma unroll
  for (int i = 0; i < 13; ++i) {
    int idx = i * 256 + t;
    if (idx < 3200 && gbase + idx < 1250000) ov[gbase + idx] = shv[idx];
  }
}

// -------- reduce: red16[n][f] = fp16(sum over in-edges of h16[src][f]*w) --------
// wave per node; lanes 0..24 own 4 features (uint2 = 4 fp16). Unroll x8:
// 8 independent gathers in flight (R13: 66us @ 3.67TB/s, 52% of achievable,
// VALUBusy 30% -> MLP-starved). ep loads are wave-uniform -> scalar pipe;
// gather addr = uniform row base + fixed lane offset.
__global__ __launch_bounds__(256) void k_reduce(const unsigned short* __restrict__ h16,
                                                const int* __restrict__ offs,
                                                const int2* __restrict__ ep,
                                                unsigned int* __restrict__ red16) {
  int wid = (blockIdx.x * 256 + threadIdx.x) >> 6;
  int node = __builtin_amdgcn_readfirstlane(wid);
  int lane = threadIdx.x & 63;
  int lc = lane < 25 ? lane : 24;   // lanes 25..63 dup lane 24's line (coalesced away)
  int beg = offs[node], end = offs[node + 1];
  const uint2* __restrict__ h2 = (const uint2*)h16;   // row = 25 uint2
  float4 acc = make_float4(0.f, 0.f, 0.f, 0.f);
  int i = beg;
  for (; i + 8 <= end; i += 8) {
    int2 e0 = ep[i + 0], e1 = ep[i + 1], e2 = ep[i + 2], e3 = ep[i + 3];
    int2 e4 = ep[i + 4], e5 = ep[i + 5], e6 = ep[i + 6], e7 = ep[i + 7];
    uint2 v0 = h2[(size_t)e0.x * 25 + lc];
    uint2 v1 = h2[(size_t)e1.x * 25 + lc];
    uint2 v2 = h2[(size_t)e2.x * 25 + lc];
    uint2 v3 = h2[(size_t)e3.x * 25 + lc];
    uint2 v4 = h2[(size_t)e4.x * 25 + lc];
    uint2 v5 = h2[(size_t)e5.x * 25 + lc];
    uint2 v6 = h2[(size_t)e6.x * 25 + lc];
    uint2 v7 = h2[(size_t)e7.x * 25 + lc];
    float w0 = __int_as_float(e0.y), w1 = __int_as_float(e1.y);
    float w2 = __int_as_float(e2.y), w3 = __int_as_float(e3.y);
    float w4 = __int_as_float(e4.y), w5 = __int_as_float(e5.y);
    float w6 = __int_as_float(e6.y), w7 = __int_as_float(e7.y);
    float2 a0 = up_f16(v0.x), b0 = up_f16(v0.y);
    float2 a1 = up_f16(v1.x), b1 = up_f16(v1.y);
    float2 a2 = up_f16(v2.x), b2 = up_f16(v2.y);
    float2 a3 = up_f16(v3.x), b3 = up_f16(v3.y);
    float2 a4 = up_f16(v4.x), b4 = up_f16(v4.y);
    float2 a5 = up_f16(v5.x), b5 = up_f16(v5.y);
    float2 a6 = up_f16(v6.x), b6 = up_f16(v6.y);
    float2 a7 = up_f16(v7.x), b7 = up_f16(v7.y);
    acc.x = fmaf(w0, a0.x, acc.x); acc.y = fmaf(w0, a0.y, acc.y);
    acc.z = fmaf(w0, b0.x, acc.z); acc.w = fmaf(w0, b0.y, acc.w);
    acc.x = fmaf(w1, a1.x, acc.x); acc.y = fmaf(w1, a1.y, acc.y);
    acc.z = fmaf(w1, b1.x, acc.z); acc.w = fmaf(w1, b1.y, acc.w);
    acc.x = fmaf(w2, a2.x, acc.x); acc.y = fmaf(w2, a2.y, acc.y);
    acc.z = fmaf(w2, b2.x, acc.z); acc.w = fmaf(w2, b2.y, acc.w);
    acc.x = fmaf(w3, a3.x, acc.x); acc.y = fmaf(w3, a3.y, acc.y);
    acc.z = fmaf(w3, b3.x, acc.z); acc.w = fmaf(w3, b3.y, acc.w);
    acc.x = fmaf(w4, a4.x, acc.x); acc.y = fmaf(w4, a4.y, acc.y);
    acc.z = fmaf(w4, b4.x, acc.z); acc.w = fmaf(w4, b4.y, acc.w);
    acc.x = fmaf(w5, a5.x, acc.x); acc.y = fmaf(w5, a5.y, acc.y);
    acc.z = fmaf(w5, b5.x, acc.z); acc.w = fmaf(w5, b5.y, acc.w);
    acc.x = fmaf(w6, a6.x, acc.x); acc.y = fmaf(w6, a6.y, acc.y);
    acc.z = fmaf(w6, b6.x, acc.z); acc.w = fmaf(w6, b6.y, acc.w);
    acc.x = fmaf(w7, a7.x, acc.x); acc.y = fmaf(w7, a7.y, acc.y);
    acc.z = fmaf(w7, b7.x, acc.z); acc.w = fmaf(w7, b7.y, acc.w);
  }
  for (; i + 4 <= end; i += 4) {
    int2 e0 = ep[i + 0], e1 = ep[i + 1], e2 = ep[i + 2], e3 = ep[i + 3];
    uint2 v0 = h2[(size_t)e0.x * 25 + lc];
    uint2 v1 = h2[(size_t)e1.x * 25 + lc];
    uint2 v2 = h2[(size_t)e2.x * 25 + lc];
    uint2 v3 = h2[(size_t)e3.x * 25 + lc];
    float w0 = __int_as_float(e0.y), w1 = __int_as_float(e1.y);
    float w2 = __int_as_float(e2.y), w3 = __int_as_float(e3.y);
    float2 a0 = up_f16(v0.x), b0 = up_f16(v0.y);
    float2 a1 = up_f16(v1.x), b1 = up_f16(v1.y);
    float2 a2 = up_f16(v2.x), b2 = up_f16(v2.y);
    float2 a3 = up_f16(v3.x), b3 = up_f16(v3.y);
    acc.x = fmaf(w0, a0.x, acc.x); acc.y = fmaf(w0, a0.y, acc.y);
    acc.z = fmaf(w0, b0.x, acc.z); acc.w = fmaf(w0, b0.y, acc.w);
    acc.x = fmaf(w1, a1.x, acc.x); acc.y = fmaf(w1, a1.y, acc.y);
    acc.z = fmaf(w1, b1.x, acc.z); acc.w = fmaf(w1, b1.y, acc.w);
    acc.x = fmaf(w2, a2.x, acc.x); acc.y = fmaf(w2, a2.y, acc.y);
    acc.z = fmaf(w2, b2.x, acc.z); acc.w = fmaf(w2, b2.y, acc.w);
    acc.x = fmaf(w3, a3.x, acc.x); acc.y = fmaf(w3, a3.y, acc.y);
    acc.z = fmaf(w3, b3.x, acc.z); acc.w = fmaf(w3, b3.y, acc.w);
  }
  for (; i < end; ++i) {
    int2 e0 = ep[i];
    uint2 v0 = h2[(size_t)e0.x * 25 + lc];
    float w0 = __int_as_float(e0.y);
    float2 a0 = up_f16(v0.x), b0 = up_f16(v0.y);
    acc.x = fmaf(w0, a0.x, acc.x); acc.y = fmaf(w0, a0.y, acc.y);
    acc.z = fmaf(w0, b0.x, acc.z); acc.w = fmaf(w0, b0.y, acc.w);
  }
  if (lane < 25) {
    ((uint2*)red16)[(size_t)node * 25 + lane] =
        make_uint2(pk_f16(acc.x, acc.y), pk_f16(acc.z, acc.w));
  }
}

// -------- mlp (MFMA): out16 = fp16(relu([h|r] @ W + b)) --------
// C/D mapping (m89-verified): col = lane&15, row = (lane>>4)*4 + reg.
__global__ __launch_bounds__(256) void k_mlp(const unsigned int* __restrict__ hp,
                                             const unsigned int* __restrict__ rp,
                                             const uint4* __restrict__ Bpk,
                                             const float* __restrict__ bias,
                                             unsigned short* __restrict__ out16) {
  __shared__ unsigned int xs[64 * 132];
  const int t = threadIdx.x;
  const int w = t >> 6, lane = t & 63;
  const int blk = blockIdx.x;
  const size_t base2 = (size_t)blk * 3200;
  const size_t limit2 = (size_t)NN * 50;

  for (int i = t; i < 64 * 28; i += 256) {
    int row = i / 28, c = i % 28;
    int col = (c < 14) ? (50 + c) : (100 + c);
    xs[row * 132 + col] = 0;
  }
  for (int i = t; i < 3200; i += 256) {
    int row = i / 50, c = i % 50;
    size_t g = base2 + i; if (g >= limit2) g = limit2 - 1;
    xs[row * 132 + c] = hp[g];
    xs[row * 132 + 64 + c] = rp[g];
  }
  __syncthreads();

  const int rowA = (w << 4) + (lane & 15);
  const int kg = lane >> 4;
  f32x4 acc[7];
  #pragma unroll
  for (int n = 0; n < 7; ++n) {
    int c = n * 16 + (lane & 15);
    float bv = (c < HID) ? bias[c] : 0.f;
    acc[n] = (f32x4){bv, bv, bv, bv};
  }
  const uint4* bp = Bpk + lane;
  #pragma unroll
  for (int s = 0; s < 8; ++s) {
    uint4 av = *reinterpret_cast<const uint4*>(&xs[rowA * 132 + s * 16 + kg * 4]);
    f16x8 af = as_f16x8(av);
    #pragma unroll
    for (int n = 0; n < 7; ++n) {
      f16x8 bf = as_f16x8(bp[(s * 7 + n) * 64]);
      acc[n] = __builtin_amdgcn_mfma_f32_16x16x32_f16(af, bf, acc[n], 0, 0, 0);
    }
  }
  const int orow0 = blk * 64 + (w << 4) + (kg << 2);
  const int ocol = lane & 15;
  #pragma unroll
  for (int n = 0; n < 7; ++n) {
    int c = n * 16 + ocol;
    if (c < HID) {
      #pragma unroll
      for (int q = 0; q < 4; ++q) {
        int rr = orow0 + q;
        if (rr < NN) {
          float v = fmaxf(acc[n][q], 0.f);
          out16[(size_t)rr * HID + c] = __half_as_ushort(__float2half(v));
        }
      }
    }
  }
}

// -------- out: sigmoid(h16 @ Wo + bo), thread per node --------
__global__ __launch_bounds__(256) void k_out(const unsigned short* __restrict__ h16,
                                             const float* __restrict__ Wo,
                                             const float* __restrict__ bo,
                                             float* __restrict__ out) {
  int n = blockIdx.x * 256 + threadIdx.x;
  if (n >= NN) return;
  float a0 = bo[0], a1 = bo[1], a2 = bo[2];
  const uint2* hr = (const uint2*)(h16 + (size_t)n * HID);
  for (int k2 = 0; k2 < 25; ++k2) {
    uint2 v = hr[k2];
    float2 fa = up_f16(v.x), fb = up_f16(v.y);
    int k = k2 * 4;
    a0 = fmaf(fa.x, Wo[(k + 0) * 3 + 0], a0); a1 = fmaf(fa.x, Wo[(k + 0) * 3 + 1], a1); a2 = fmaf(fa.x, Wo[(k + 0) * 3 + 2], a2);
    a0 = fmaf(fa.y, Wo[(k + 1) * 3 + 0], a0); a1 = fmaf(fa.y, Wo[(k + 1) * 3 + 1], a1); a2 = fmaf(fa.y, Wo[(k + 1) * 3 + 2], a2);
    a0 = fmaf(fb.x, Wo[(k + 2) * 3 + 0], a0); a1 = fmaf(fb.x, Wo[(k + 2) * 3 + 1], a1); a2 = fmaf(fb.x, Wo[(k + 2) * 3 + 2], a2);
    a0 = fmaf(fb.y, Wo[(k + 3) * 3 + 0], a0); a1 = fmaf(fb.y, Wo[(k + 3) * 3 + 1], a1); a2 = fmaf(fb.y, Wo[(k + 3) * 3 + 2], a2);
  }
  out[(size_t)n * 3 + 0] = 1.f / (1.f + expf(-a0));
  out[(size_t)n * 3 + 1] = 1.f / (1.f + expf(-a1));
  out[(size_t)n * 3 + 2] = 1.f / (1.f + expf(-a2));
}

extern "C" void kernel_launch(void* const* d_in, const int* in_sizes, int n_in,
                              void* d_out, int out_size, void* d_ws, size_t ws_size,
                              hipStream_t stream) {
  const float* x  = (const float*)d_in[0];
  const float* ef = (const float*)d_in[1];
  const int*   src = (const int*)d_in[2];
  const int*   dst = (const int*)d_in[3];
  const float* Wl = (const float*)d_in[4];
  const float* bl = (const float*)d_in[5];
  const float* W1 = (const float*)d_in[6];
  const float* b1 = (const float*)d_in[7];
  const float* W2 = (const float*)d_in[8];
  const float* b2 = (const float*)d_in[9];
  const float* W3 = (const float*)d_in[10];
  const float* b3 = (const float*)d_in[11];
  const float* Wo = (const float*)d_in[12];
  const float* bo = (const float*)d_in[13];
  float* out = (float*)d_out;

  // workspace layout (~93.6 MB)
  char* ws = (char*)d_ws;
  unsigned int*   red16  = (unsigned int*)(ws);                 // 20,000,000 B (fp16 reduce out)
  uint4*          Wpk    = (uint4*)(ws + 20000000);             // 3 x 57,344 B
  unsigned short* hA16   = (unsigned short*)(ws + 40000000);    // 20,000,000 B
  unsigned short* hB16   = (unsigned short*)(ws + 60000000);    // 20,000,000 B
  int*            offs   = (int*)(ws + 80000000);               // (NN+1)*4
  int*            deg    = (int*)(ws + 80400128);               // NN*4
  unsigned long long* epack = (unsigned long long*)(ws + 80800256); // NE*8
  int*            bsum   = (int*)(ws + 93600256);               // 391*4
  // rank aliases red16 (consumed by k_fill BEFORE first k_reduce)
  int*            rank   = (int*)ws;                            // 6,400,000 B

  const int scanBlocks = (NN + 255) / 256;          // 391
  const int mlpBlocks  = (NN + 63) / 64;            // 1563
  uint4* Wpk1 = Wpk;                                // 3584 uint4 each
  uint4* Wpk2 = Wpk + 3584;
  uint4* Wpk3 = Wpk + 7168;

  // ---- CSR build (simple hist + rank trick, atomic-free fill) ----
  hipMemsetAsync(deg, 0, NN * sizeof(int), stream);
  k_hist <<<(NE + 255) / 256, 256, 0, stream>>>(dst, deg, rank);
  k_scan1<<<scanBlocks, 256, 0, stream>>>(deg, offs, bsum);
  k_scan2<<<1, 512, 0, stream>>>(bsum, scanBlocks);
  k_scan3<<<scanBlocks, 256, 0, stream>>>(offs, bsum);
  k_fill <<<(NE + 255) / 256, 256, 0, stream>>>(src, dst, ef, offs, rank, epack);

  // ---- W fragment pre-pack (fp16) ----
  k_wpack<<<14, 256, 0, stream>>>(W1, Wpk1);
  k_wpack<<<14, 256, 0, stream>>>(W2, Wpk2);
  k_wpack<<<14, 256, 0, stream>>>(W3, Wpk3);

  // ---- network ----
  k_lift<<<scanBlocks, 256, 0, stream>>>(x, Wl, bl, hA16);

  k_reduce<<<NN / 4, 256, 0, stream>>>(hA16, offs, (const int2*)epack, red16);
  k_mlp   <<<mlpBlocks, 256, 0, stream>>>((const unsigned int*)hA16, red16, Wpk1, b1, hB16);

  k_reduce<<<NN / 4, 256, 0, stream>>>(hB16, offs, (const int2*)epack, red16);
  k_mlp   <<<mlpBlocks, 256, 0, stream>>>((const unsigned int*)hB16, red16, Wpk2, b2, hA16);

  k_reduce<<<NN / 4, 256, 0, stream>>>(hA16, offs, (const int2*)epack, red16);
  k_mlp   <<<mlpBlocks, 256, 0, stream>>>((const unsigned int*)hA16, red16, Wpk3, b3, hB16);

  k_out<<<scanBlocks, 256, 0, stream>>>(hB16, Wo, bo, out);
}